// Round 4
// baseline (8361.051 us; speedup 1.0000x reference)
//
#include <hip/hip_runtime.h>
#include <math.h>

namespace {

constexpr int TPB  = 512;
constexpr int NB   = 256;   // batch
constexpr int NT   = 1000;  // time steps
constexpr int NX   = 64;    // state dim
constexpr int NS   = 4;     // control dim
constexpr int DIN  = 68;    // NX + NS
constexpr int HF   = 256;
constexpr int HG   = 128;
constexpr float DTC   = 0.01f;
constexpr float SIGMA = 0.1f;

constexpr int HPAD  = 288;  // padded h storage: idx + (idx>>5)*4
constexpr int WG1LD = 132;  // s_wg1 row stride [k][c]
constexpr int WG2T  = 132;  // s_wg2t row stride [c][k] (transposed)
constexpr int CH    = 68;   // dW/out chunk row stride

typedef float v2f __attribute__((ext_vector_type(2)));

__device__ __forceinline__ int pmap(int i){ return i + ((i>>5)<<2); }

template<int CTRL>
__device__ __forceinline__ float dpp_add(float x){
    int y = __builtin_amdgcn_update_dpp(0, __float_as_int(x), CTRL, 0xF, 0xF, true);
    return x + __int_as_float(y);
}
// sum over lanes t^1, t^2 (quad) — pure VALU (DPP)
__device__ __forceinline__ float quad_sum(float x){
    x = dpp_add<0xB1>(x);   // quad_perm [1,0,3,2] : xor 1
    x = dpp_add<0x4E>(x);   // quad_perm [2,3,0,1] : xor 2
    return x;
}
// + lanes t^4 via ds_swizzle (single LDS-pipe op)
__device__ __forceinline__ float swz4_add(float x){
    int y = __builtin_amdgcn_ds_swizzle(__float_as_int(x), 0x101F); // xor 4
    return x + __int_as_float(y);
}
__device__ __forceinline__ float oct_sum(float x){ return swz4_add(quad_sum(x)); }

__device__ __forceinline__ float tanh_fast(float x){
    // tanh(x) = 1 - 2/(e^{2x}+1);  rcp is 1-ulp v_rcp_f32. Handles +/-inf.
    float e = __expf(2.0f*x);
    float r = __builtin_amdgcn_rcpf(e + 1.0f);
    return __builtin_fmaf(-2.0f, r, 1.0f);
}
__device__ __forceinline__ float softplus_f(float x){
    return fmaxf(x,0.0f) + log1pf(__expf(-fabsf(x)));
}

__device__ __forceinline__ v2f pkfma(v2f a, v2f b, v2f c){
    return __builtin_elementwise_fma(a, b, c);   // v_pk_fma_f32
}

// One workgroup = one batch element for all 1000 steps. 12 barriers/step.
// K-split reductions: xor1/xor2 via DPP (VALU), xor4 via ds_swizzle.
__global__ __launch_bounds__(TPB, 2) void sde_rk4_kernel(
    const float* __restrict__ gIn, const float* __restrict__ gNz,
    const float* __restrict__ Wf1, const float* __restrict__ bf1,
    const float* __restrict__ Wf2, const float* __restrict__ bf2,
    const float* __restrict__ Wf3, const float* __restrict__ bf3,
    const float* __restrict__ Wg1, const float* __restrict__ bg1,
    const float* __restrict__ Wg2, const float* __restrict__ bg2,
    float* __restrict__ gOut)
{
    const int b = blockIdx.x;
    const int t = threadIdx.x;

    __shared__ __align__(16) float s_z[72];        // [X(64), u(4), pad]
    __shared__ __align__(16) float s_h1[HPAD];
    __shared__ __align__(16) float s_h2[HPAD];
    __shared__ __align__(16) float s_hg[HG];
    __shared__ __align__(16) float s_uall[4008];   // u[step][4]
    __shared__ __align__(16) float s_dwc[NX*CH];   // dW chunk [x][64]
    __shared__ __align__(16) float s_out[NX*CH];   // out buffer [x][64]
    __shared__ __align__(16) float s_wg1[DIN*WG1LD];  // [k][c]
    __shared__ __align__(16) float s_wg2t[NX*WG2T];   // [c][k] transposed

    // ---- thread roles ----
    // L1: cols {2gA,2gA+1}, 4-way K-split (16/16/16/20), partners xor1,2 (quad)
    const int gA = t>>2, sA = t&3;  const int cA0 = 2*gA;  const int k0A = 16*sA;
    const int lenA = (sA==3)?20:16;
    // L2: cols {4gB..+3}, 8-way K-split (32 each), partners xor1,2,4
    const int gB = t>>3, sB = t&7;  const int cB0 = 4*gB;  const int k0B = 32*sB;
    // L3 / G2 / state owner: col cC, 8-way K-split
    const int cC = t>>3, sC = t&7;  const int k0C = 32*sC; const int k0H = 16*sC;
    // G1: col cG, 4-way K-split (17 each)
    const int cG = t>>2;            const int k0G = 17*sA;
    const bool owner = (sC==0);
    const int rD = t>>3, j0D = (t&7)*8;   // chunk load/flush roles

    // ---- F-weights -> registers (packed pairs, zero-padded) ----
    v2f wf1r[20];
#pragma unroll
    for (int k=0;k<20;++k){
        v2f w = {0.f, 0.f};
        if (k < lenA) w = *(const v2f*)&Wf1[(k0A+k)*HF + cA0];
        wf1r[k] = w;
    }
    v2f wf2r[32][2];
#pragma unroll
    for (int k=0;k<32;++k){
        const float4 wv = *(const float4*)&Wf2[(size_t)(k0B+k)*HF + cB0];
        wf2r[k][0] = (v2f){wv.x, wv.y};
        wf2r[k][1] = (v2f){wv.z, wv.w};
    }
    v2f wf3p[16];
#pragma unroll
    for (int j=0;j<16;++j){
        wf3p[j] = (v2f){ Wf3[(k0C+2*j)*NX + cC], Wf3[(k0C+2*j+1)*NX + cC] };
    }

    const float2 bf1v = *(const float2*)&bf1[cA0];
    const float4 bf2v = *(const float4*)&bf2[cB0];
    const float bf3c = bf3[cC];
    const float bg1c = bg1[cG];
    const float bg2c = bg2[cC];

    const float sq = sqrtf(DTC);
    const float* inB = gIn + (size_t)b*DIN*NT;
    const float* nzB = gNz + (size_t)b*NX*NT;
    float*      outB = gOut + (size_t)b*NX*NT;

    // ---- G-weights -> LDS, u sequence -> LDS ----
    for (int i=t;i<DIN*HG;i+=TPB){ const int k=i>>7, c=i&(HG-1); s_wg1[k*WG1LD+c] = Wg1[i]; }
    for (int i=t;i<HG*NX; i+=TPB){ const int k=i>>6, c=i&(NX-1); s_wg2t[c*WG2T+k] = Wg2[i]; }
    for (int i=t;i<NS*NT; i+=TPB) s_uall[i] = inB[(i&3)*NT + (i>>2)];
    if (t<8)            s_uall[NS*NT+t] = 0.f;
    if (t>=68 && t<72)  s_z[t] = 0.f;
    if (t<4)            s_z[64+t] = inB[t*NT];
    float X=0.f, kacc=0.f, gc=0.f;
    if (owner){ X = inB[(size_t)(NS+cC)*NT]; s_z[cC] = X; }
    __syncthreads();

    // ---------- phases ----------
    auto phaseA = [&](bool withG){
        v2f acc = {0.f, 0.f};
#pragma unroll
        for (int q=0;q<5;++q){                       // zero-padded beyond lenA
            const float4 zv = *(const float4*)&s_z[k0A + 4*q];
            acc = pkfma((v2f){zv.x,zv.x}, wf1r[4*q+0], acc);
            acc = pkfma((v2f){zv.y,zv.y}, wf1r[4*q+1], acc);
            acc = pkfma((v2f){zv.z,zv.z}, wf1r[4*q+2], acc);
            acc = pkfma((v2f){zv.w,zv.w}, wf1r[4*q+3], acc);
        }
        float q0 = 0.f;
        if (withG){
#pragma unroll
            for (int k=0;k<17;++k)
                q0 = fmaf(s_z[k0G+k], s_wg1[(k0G+k)*WG1LD + cG], q0);
            q0 = quad_sum(q0);
        }
        const float r0 = quad_sum(acc[0]);
        const float r1 = quad_sum(acc[1]);
        if (sA==0){
            float2 hv = { tanh_fast(r0 + bf1v.x), tanh_fast(r1 + bf1v.y) };
            *(float2*)&s_h1[pmap(cA0)] = hv;
            if (withG) s_hg[cG] = tanh_fast(q0 + bg1c);
        }
        __syncthreads();
    };

    auto phaseB = [&](bool withG){
        v2f a0={0.f,0.f}, a1={0.f,0.f};
        const float* h1p = &s_h1[36*sB];             // pmap(32*sB+j) = 36*sB+j
#pragma unroll
        for (int q=0;q<8;++q){
            const float4 hv = *(const float4*)&h1p[4*q];
            a0 = pkfma((v2f){hv.x,hv.x}, wf2r[4*q+0][0], a0);
            a1 = pkfma((v2f){hv.x,hv.x}, wf2r[4*q+0][1], a1);
            a0 = pkfma((v2f){hv.y,hv.y}, wf2r[4*q+1][0], a0);
            a1 = pkfma((v2f){hv.y,hv.y}, wf2r[4*q+1][1], a1);
            a0 = pkfma((v2f){hv.z,hv.z}, wf2r[4*q+2][0], a0);
            a1 = pkfma((v2f){hv.z,hv.z}, wf2r[4*q+2][1], a1);
            a0 = pkfma((v2f){hv.w,hv.w}, wf2r[4*q+3][0], a0);
            a1 = pkfma((v2f){hv.w,hv.w}, wf2r[4*q+3][1], a1);
        }
        const float c0 = oct_sum(a0[0]);
        const float c1 = oct_sum(a0[1]);
        const float c2 = oct_sum(a1[0]);
        const float c3 = oct_sum(a1[1]);
        float gq = 0.f;
        if (withG){
            v2f g2 = {0.f,0.f};
            const float* wtp = &s_wg2t[cC*WG2T + k0H];
            const float* hgp = &s_hg[k0H];
#pragma unroll
            for (int q=0;q<4;++q){
                const float4 wv = *(const float4*)&wtp[4*q];
                const float4 hv = *(const float4*)&hgp[4*q];
                g2 = pkfma((v2f){hv.x,hv.y}, (v2f){wv.x,wv.y}, g2);
                g2 = pkfma((v2f){hv.z,hv.w}, (v2f){wv.z,wv.w}, g2);
            }
            gq = oct_sum(g2[0] + g2[1]);
        }
        if (sB==0){
            float4 hv;
            hv.x = tanh_fast(c0 + bf2v.x);
            hv.y = tanh_fast(c1 + bf2v.y);
            hv.z = tanh_fast(c2 + bf2v.z);
            hv.w = tanh_fast(c3 + bf2v.w);
            *(float4*)&s_h2[pmap(cB0)] = hv;
        }
        if (withG && owner) gc = SIGMA*softplus_f(gq + bg2c);
        __syncthreads();
    };

    auto phaseC = [&](int ev, int st){
        v2f e = {0.f, 0.f};
        const float* h2p = &s_h2[36*sC];
#pragma unroll
        for (int q=0;q<8;++q){
            const float4 hv = *(const float4*)&h2p[4*q];
            e = pkfma((v2f){hv.x,hv.y}, wf3p[2*q+0], e);
            e = pkfma((v2f){hv.z,hv.w}, wf3p[2*q+1], e);
        }
        const float ks = oct_sum(e[0] + e[1]);
        if (owner){
            const float kv = ks + bf3c;
            if (ev==0)      kacc = kv;
            else if (ev==3) kacc += kv;
            else            kacc += 2.0f*kv;
            if (ev<3){
                s_z[cC] = fmaf((ev==2)?DTC:0.5f*DTC, kv, X);
            } else {
                const int jj = st & 63;
                const float dw = s_dwc[cC*CH + jj];
                X = X + (DTC/6.0f)*kacc + gc*dw;
                s_z[cC] = X;
                s_out[cC*CH + jj] = X;
                if (cC < NS) s_z[64+cC] = s_uall[(st+1)*4 + cC];
            }
        }
        __syncthreads();
    };

    // ---------- main loop ----------
#pragma unroll 1
    for (int st=0; st<NT; ++st){
        if ((st & 63) == 0){
            if (st + 64 <= NT){
                const float4 v0 = *(const float4*)&nzB[(size_t)rD*NT + st + j0D];
                const float4 v1 = *(const float4*)&nzB[(size_t)rD*NT + st + j0D + 4];
                float* d = &s_dwc[rD*CH + j0D];
                d[0]=v0.x*sq; d[1]=v0.y*sq; d[2]=v0.z*sq; d[3]=v0.w*sq;
                d[4]=v1.x*sq; d[5]=v1.y*sq; d[6]=v1.z*sq; d[7]=v1.w*sq;
            } else {
#pragma unroll
                for (int e=0;e<8;++e){
                    const int j = j0D + e;
                    const float v = (st + j < NT) ? nzB[(size_t)rD*NT + st + j] : 0.f;
                    s_dwc[rD*CH + j] = v*sq;
                }
            }
        }

        phaseA(true);  phaseB(true);  phaseC(0, st);
#pragma unroll
        for (int ev=1; ev<4; ++ev){
            phaseA(false); phaseB(false); phaseC(ev, st);
        }

        const int jj = st & 63;
        if (jj == 63 || st == NT-1){
            const int st0 = st & ~63;
            const int cnt = st - st0 + 1;
            if (cnt == 64){
                const float4 w0 = *(const float4*)&s_out[rD*CH + j0D];
                const float4 w1 = *(const float4*)&s_out[rD*CH + j0D + 4];
                *(float4*)&outB[(size_t)rD*NT + st0 + j0D]     = w0;
                *(float4*)&outB[(size_t)rD*NT + st0 + j0D + 4] = w1;
            } else {
#pragma unroll
                for (int e=0;e<8;++e){
                    const int j = j0D + e;
                    if (j < cnt) outB[(size_t)rD*NT + st0 + j] = s_out[rD*CH + j];
                }
            }
        }
    }
}

} // namespace

extern "C" void kernel_launch(void* const* d_in, const int* in_sizes, int n_in,
                              void* d_out, int out_size, void* d_ws, size_t ws_size,
                              hipStream_t stream)
{
    const float* Inputs = (const float*)d_in[0];
    const float* noise  = (const float*)d_in[1];
    // d_in[2] = t0 (unused)
    const float* Wf1 = (const float*)d_in[3];
    const float* bf1 = (const float*)d_in[4];
    const float* Wf2 = (const float*)d_in[5];
    const float* bf2 = (const float*)d_in[6];
    const float* Wf3 = (const float*)d_in[7];
    const float* bf3 = (const float*)d_in[8];
    const float* Wg1 = (const float*)d_in[9];
    const float* bg1 = (const float*)d_in[10];
    const float* Wg2 = (const float*)d_in[11];
    const float* bg2 = (const float*)d_in[12];
    float* out = (float*)d_out;

    sde_rk4_kernel<<<dim3(NB), dim3(TPB), 0, stream>>>(
        Inputs, noise, Wf1, bf1, Wf2, bf2, Wf3, bf3, Wg1, bg1, Wg2, bg2, out);
}

// Round 5
// 7855.049 us; speedup vs baseline: 1.0644x; 1.0644x over previous
//
#include <hip/hip_runtime.h>
#include <math.h>

namespace {

constexpr int TPB  = 512;
constexpr int NB   = 256;   // batch
constexpr int NT   = 1000;  // time steps
constexpr int NX   = 64;    // state dim
constexpr int NS   = 4;     // control dim
constexpr int DIN  = 68;    // NX + NS
constexpr int HF   = 256;
constexpr int HG   = 128;
constexpr float DTC   = 0.01f;
constexpr float SIGMA = 0.1f;

constexpr int HPAD = 288;   // padded h storage: idx + (idx>>5)*4
constexpr int CH   = 68;    // dW/out chunk row stride

typedef float v2f __attribute__((ext_vector_type(2)));

__device__ __forceinline__ int pmap(int i){ return i + ((i>>5)<<2); }

template<int CTRL>
__device__ __forceinline__ float dpp_add(float x){
    int y = __builtin_amdgcn_update_dpp(0, __float_as_int(x), CTRL, 0xF, 0xF, true);
    return x + __int_as_float(y);
}
// sum over lanes t^1, t^2 — quad_perm DPP (VALU pipe)
__device__ __forceinline__ float quad_sum(float x){
    x = dpp_add<0xB1>(x);   // quad_perm [1,0,3,2] : xor 1
    x = dpp_add<0x4E>(x);   // quad_perm [2,3,0,1] : xor 2
    return x;
}
// oct group = lane bits {0,1,3}: xor1, xor2 (quad_perm) + xor8 (row_ror:8) — ALL DPP
__device__ __forceinline__ float oct_sum(float x){
    x = quad_sum(x);
    x = dpp_add<0x128>(x);  // row_ror:8 : lane l <-> l^8 within 16-lane row
    return x;
}

__device__ __forceinline__ float tanh_fast(float x){
    float e = __expf(2.0f*x);
    float r = __builtin_amdgcn_rcpf(e + 1.0f);
    return __builtin_fmaf(-2.0f, r, 1.0f);
}
__device__ __forceinline__ float softplus_f(float x){
    // max(x,0) + log(1+exp(-|x|)); abs err <= ~6e-8
    return fmaxf(x,0.0f) + __logf(1.0f + __expf(-fabsf(x)));
}

__device__ __forceinline__ v2f pkfma(v2f a, v2f b, v2f c){
    return __builtin_elementwise_fma(a, b, c);   // v_pk_fma_f32
}

// One workgroup = one batch element for all 1000 steps. 12 barriers/step.
// All K-split reductions pure DPP; all weights register-resident except none.
__global__ __launch_bounds__(TPB, 2) void sde_rk4_kernel(
    const float* __restrict__ gIn, const float* __restrict__ gNz,
    const float* __restrict__ Wf1, const float* __restrict__ bf1,
    const float* __restrict__ Wf2, const float* __restrict__ bf2,
    const float* __restrict__ Wf3, const float* __restrict__ bf3,
    const float* __restrict__ Wg1, const float* __restrict__ bg1,
    const float* __restrict__ Wg2, const float* __restrict__ bg2,
    float* __restrict__ gOut)
{
    const int b = blockIdx.x;
    const int t = threadIdx.x;

    __shared__ __align__(16) float s_z[72];        // [X(64), u(4), pad]
    __shared__ __align__(16) float s_h1[HPAD];
    __shared__ __align__(16) float s_h2[HPAD];
    __shared__ __align__(16) float s_hg[HG];
    __shared__ __align__(16) float s_uall[4008];   // u[step][4] (+pad)
    __shared__ __align__(16) float s_dwc[NX*CH];   // dW chunk [x][64]
    __shared__ __align__(16) float s_out[NX*CH];   // out buffer [x][64]

    // ---- thread roles ----
    const int q2 = t & 3;                                   // quad slice id
    const int s8 = (t & 3) | (((t >> 3) & 1) << 2);         // oct slice id (bits t0,t1,t3)
    const int gA = t >> 2;          const int cA0 = 2*gA;   // L1/G1 col group (128)
    const int k0A = 16*q2;          const int lenA = (q2==3)?20:16;
    const int gB = ((t>>2)&1) | ((t>>4)<<1);                // oct col group (64)
    const int cB0 = 4*gB;           const int k0B = 32*s8;  // L2
    const int cC  = gB;             const int k0C = 32*s8;  // L3
    const int k0H = 16*s8;                                  // G2 k-slice
    const int cG  = gA;                                     // G1 col
    const bool oct0  = (s8 == 0);
    const bool quad0 = (q2 == 0);
    const int rD = t>>3, j0D = (t&7)*8;                     // chunk load/flush roles

    // ---- weights -> registers (zero-padded slices) ----
    v2f wf1r[20];
    float wg1r[20];
#pragma unroll
    for (int k=0;k<20;++k){
        v2f w = {0.f, 0.f}; float wg = 0.f;
        if (k < lenA){
            w  = *(const v2f*)&Wf1[(k0A+k)*HF + cA0];
            wg = Wg1[(k0A+k)*HG + cG];
        }
        wf1r[k] = w; wg1r[k] = wg;
    }
    v2f wf2r[32][2];
#pragma unroll
    for (int k=0;k<32;++k){
        const float4 wv = *(const float4*)&Wf2[(size_t)(k0B+k)*HF + cB0];
        wf2r[k][0] = (v2f){wv.x, wv.y};
        wf2r[k][1] = (v2f){wv.z, wv.w};
    }
    v2f wf3p[16];
#pragma unroll
    for (int j=0;j<16;++j){
        wf3p[j] = (v2f){ Wf3[(k0C+2*j)*NX + cC], Wf3[(k0C+2*j+1)*NX + cC] };
    }
    float wg2r[16];
#pragma unroll
    for (int k=0;k<16;++k) wg2r[k] = Wg2[(k0H+k)*NX + cC];

    const float2 bf1v = *(const float2*)&bf1[cA0];
    const float4 bf2v = *(const float4*)&bf2[cB0];
    const float bf3c = bf3[cC];
    const float bg1c = bg1[cG];
    const float bg2c = bg2[cC];

    const float sq = sqrtf(DTC);
    const float* inB = gIn + (size_t)b*DIN*NT;
    const float* nzB = gNz + (size_t)b*NX*NT;
    float*      outB = gOut + (size_t)b*NX*NT;

    // ---- u sequence -> LDS; initial state ----
    for (int i=t;i<NS*NT; i+=TPB) s_uall[i] = inB[(i&3)*NT + (i>>2)];
    if (t<8)            s_uall[NS*NT+t] = 0.f;
    if (t>=68 && t<72)  s_z[t] = 0.f;
    if (t<4)            s_z[64+t] = inB[t*NT];
    float X = inB[(size_t)(NS+cC)*NT];   // replicated across oct group
    float kacc = 0.f, gc = 0.f;
    if (oct0) s_z[cC] = X;
    __syncthreads();

    // ---------- phases ----------
    auto phaseA = [&](bool withG){
        v2f acc = {0.f, 0.f};
        float ag = 0.f;
#pragma unroll
        for (int q=0;q<5;++q){                 // weights zero-padded beyond lenA
            const float4 zv = *(const float4*)&s_z[k0A + 4*q];
            acc = pkfma((v2f){zv.x,zv.x}, wf1r[4*q+0], acc);
            acc = pkfma((v2f){zv.y,zv.y}, wf1r[4*q+1], acc);
            acc = pkfma((v2f){zv.z,zv.z}, wf1r[4*q+2], acc);
            acc = pkfma((v2f){zv.w,zv.w}, wf1r[4*q+3], acc);
            if (withG){
                ag = fmaf(zv.x, wg1r[4*q+0], ag);
                ag = fmaf(zv.y, wg1r[4*q+1], ag);
                ag = fmaf(zv.z, wg1r[4*q+2], ag);
                ag = fmaf(zv.w, wg1r[4*q+3], ag);
            }
        }
        const float r0 = quad_sum(acc[0]);
        const float r1 = quad_sum(acc[1]);
        float2 hv = { tanh_fast(r0 + bf1v.x), tanh_fast(r1 + bf1v.y) };
        if (quad0) *(float2*)&s_h1[pmap(cA0)] = hv;
        if (withG){
            const float agr = quad_sum(ag);
            if (quad0) s_hg[cG] = tanh_fast(agr + bg1c);
        }
        __syncthreads();
    };

    auto phaseB = [&](bool withG){
        v2f a0={0.f,0.f}, a1={0.f,0.f};
        const float* h1p = &s_h1[36*s8];       // pmap(32*s8 + j) = 36*s8 + j
#pragma unroll
        for (int q=0;q<8;++q){
            const float4 hv = *(const float4*)&h1p[4*q];
            a0 = pkfma((v2f){hv.x,hv.x}, wf2r[4*q+0][0], a0);
            a1 = pkfma((v2f){hv.x,hv.x}, wf2r[4*q+0][1], a1);
            a0 = pkfma((v2f){hv.y,hv.y}, wf2r[4*q+1][0], a0);
            a1 = pkfma((v2f){hv.y,hv.y}, wf2r[4*q+1][1], a1);
            a0 = pkfma((v2f){hv.z,hv.z}, wf2r[4*q+2][0], a0);
            a1 = pkfma((v2f){hv.z,hv.z}, wf2r[4*q+2][1], a1);
            a0 = pkfma((v2f){hv.w,hv.w}, wf2r[4*q+3][0], a0);
            a1 = pkfma((v2f){hv.w,hv.w}, wf2r[4*q+3][1], a1);
        }
        const float c0 = oct_sum(a0[0]);
        const float c1 = oct_sum(a0[1]);
        const float c2 = oct_sum(a1[0]);
        const float c3 = oct_sum(a1[1]);
        if (withG){
            float gq = 0.f;
            const float* hgp = &s_hg[k0H];
#pragma unroll
            for (int q=0;q<4;++q){
                const float4 hv = *(const float4*)&hgp[4*q];
                gq = fmaf(hv.x, wg2r[4*q+0], gq);
                gq = fmaf(hv.y, wg2r[4*q+1], gq);
                gq = fmaf(hv.z, wg2r[4*q+2], gq);
                gq = fmaf(hv.w, wg2r[4*q+3], gq);
            }
            gq = oct_sum(gq);
            gc = SIGMA*softplus_f(gq + bg2c);  // replicated across oct
        }
        float4 hv;
        hv.x = tanh_fast(c0 + bf2v.x);
        hv.y = tanh_fast(c1 + bf2v.y);
        hv.z = tanh_fast(c2 + bf2v.z);
        hv.w = tanh_fast(c3 + bf2v.w);
        if (oct0) *(float4*)&s_h2[pmap(cB0)] = hv;
        __syncthreads();
    };

    auto phaseC = [&](int ev, int st){
        v2f e = {0.f, 0.f};
        const float* h2p = &s_h2[36*s8];
#pragma unroll
        for (int q=0;q<8;++q){
            const float4 hv = *(const float4*)&h2p[4*q];
            e = pkfma((v2f){hv.x,hv.y}, wf3p[2*q+0], e);
            e = pkfma((v2f){hv.z,hv.w}, wf3p[2*q+1], e);
        }
        const float kv = oct_sum(e[0] + e[1]) + bf3c;  // replicated across oct
        if (ev==0)      kacc = kv;
        else if (ev==3) kacc += kv;
        else            kacc += 2.0f*kv;
        if (ev<3){
            if (oct0) s_z[cC] = fmaf((ev==2)?DTC:0.5f*DTC, kv, X);
        } else {
            const int jj = st & 63;
            const float dw = s_dwc[cC*CH + jj];        // broadcast within oct
            X = X + (DTC/6.0f)*kacc + gc*dw;           // replicated update
            if (oct0){
                s_z[cC] = X;
                s_out[cC*CH + jj] = X;
                if (cC < NS) s_z[64+cC] = s_uall[(st+1)*4 + cC];
            }
        }
        __syncthreads();
    };

    // ---------- main loop ----------
#pragma unroll 1
    for (int st=0; st<NT; ++st){
        if ((st & 63) == 0){
            if (st + 64 <= NT){
                const float4 v0 = *(const float4*)&nzB[(size_t)rD*NT + st + j0D];
                const float4 v1 = *(const float4*)&nzB[(size_t)rD*NT + st + j0D + 4];
                float* d = &s_dwc[rD*CH + j0D];
                d[0]=v0.x*sq; d[1]=v0.y*sq; d[2]=v0.z*sq; d[3]=v0.w*sq;
                d[4]=v1.x*sq; d[5]=v1.y*sq; d[6]=v1.z*sq; d[7]=v1.w*sq;
            } else {
#pragma unroll
                for (int e=0;e<8;++e){
                    const int j = j0D + e;
                    const float v = (st + j < NT) ? nzB[(size_t)rD*NT + st + j] : 0.f;
                    s_dwc[rD*CH + j] = v*sq;
                }
            }
        }

        phaseA(true);  phaseB(true);  phaseC(0, st);
#pragma unroll
        for (int ev=1; ev<4; ++ev){
            phaseA(false); phaseB(false); phaseC(ev, st);
        }

        const int jj = st & 63;
        if (jj == 63 || st == NT-1){
            const int st0 = st & ~63;
            const int cnt = st - st0 + 1;
            if (cnt == 64){
                const float4 w0 = *(const float4*)&s_out[rD*CH + j0D];
                const float4 w1 = *(const float4*)&s_out[rD*CH + j0D + 4];
                *(float4*)&outB[(size_t)rD*NT + st0 + j0D]     = w0;
                *(float4*)&outB[(size_t)rD*NT + st0 + j0D + 4] = w1;
            } else {
#pragma unroll
                for (int e=0;e<8;++e){
                    const int j = j0D + e;
                    if (j < cnt) outB[(size_t)rD*NT + st0 + j] = s_out[rD*CH + j];
                }
            }
        }
    }
}

} // namespace

extern "C" void kernel_launch(void* const* d_in, const int* in_sizes, int n_in,
                              void* d_out, int out_size, void* d_ws, size_t ws_size,
                              hipStream_t stream)
{
    const float* Inputs = (const float*)d_in[0];
    const float* noise  = (const float*)d_in[1];
    // d_in[2] = t0 (unused)
    const float* Wf1 = (const float*)d_in[3];
    const float* bf1 = (const float*)d_in[4];
    const float* Wf2 = (const float*)d_in[5];
    const float* bf2 = (const float*)d_in[6];
    const float* Wf3 = (const float*)d_in[7];
    const float* bf3 = (const float*)d_in[8];
    const float* Wg1 = (const float*)d_in[9];
    const float* bg1 = (const float*)d_in[10];
    const float* Wg2 = (const float*)d_in[11];
    const float* bg2 = (const float*)d_in[12];
    float* out = (float*)d_out;

    sde_rk4_kernel<<<dim3(NB), dim3(TPB), 0, stream>>>(
        Inputs, noise, Wf1, bf1, Wf2, bf2, Wf3, bf3, Wg1, bg1, Wg2, bg2, out);
}